// Round 1
// baseline (908.917 us; speedup 1.0000x reference)
//
#include <hip/hip_runtime.h>
#include <cstdint>

// LinearGlobalAttention: out = ((elu(xWq^T)+1) @ M) * z + bo
//   M = (k^T v) @ Wo^T,  k = elu(xWk^T)+1, v = xWv^T, z = 1/max(q@ksum,1e-6)
// N=262144, C=256. Two fused passes over x + tiny mid kernels.
// MFMA 16x16x32 bf16; verified layouts: A[m=lane&15][k=(lane>>4)*8+j],
// C/D: col=lane&15, row=(lane>>4)*4+reg.

typedef __attribute__((ext_vector_type(8))) short short8;
typedef __attribute__((ext_vector_type(4))) float f32x4;
typedef unsigned short u16;
typedef unsigned int u32;

#define MFMA16(a, b, c) __builtin_amdgcn_mfma_f32_16x16x32_bf16(a, b, c, 0, 0, 0)

__device__ __forceinline__ u32 bf16_1(float f) {
  u32 u = __float_as_uint(f);
  return (u + 0x7FFFu + ((u >> 16) & 1u)) >> 16;  // RNE
}
__device__ __forceinline__ u32 bf16pk(float lo, float hi) {
  return bf16_1(lo) | (bf16_1(hi) << 16);
}

// ---------------------------------------------------------------- prep ------
// Zero ksum (+ kv partial buffers if atomics mode) and build pre-swizzled
// bf16 B-operand fragments for Wq/Wk/Wv: element (c,d) of W (y = x W^T, so
// B[k=d][n=c]=W[c][d]) goes to frag slot so a lane loads one dwordx4.
__global__ void prep_kernel(const float* __restrict__ Wq, const float* __restrict__ Wk,
                            const float* __restrict__ Wv, u16* __restrict__ WqF,
                            u16* __restrict__ WkF, u16* __restrict__ WvF,
                            float* __restrict__ kvp, float* __restrict__ ksum, int P) {
  int id = blockIdx.x * 256 + threadIdx.x;  // 65536 threads
  if (id < 256) ksum[id] = 0.f;
  for (int t = id; t < 3 * 65536; t += 65536) {
    int mat = t >> 16;
    int e = t & 65535;
    int c = e >> 8, d = e & 255;
    const float* src = (mat == 0) ? Wq : (mat == 1) ? Wk : Wv;
    u16* dst = (mat == 0) ? WqF : (mat == 1) ? WkF : WvF;
    int idx = (((c >> 5) * 8 + (d >> 5)) * 2 + ((c >> 4) & 1)) * 512 +
              ((d >> 3) & 3) * 128 + (c & 15) * 8 + (d & 7);
    dst[idx] = (u16)bf16_1(src[e]);
  }
  if (P < 256) {  // atomic mode needs zeroed accumulators
    float4 z4 = {0.f, 0.f, 0.f, 0.f};
    float4* kz = (float4*)kvp;
    int total = P * 16384;
    for (int t = id; t < total; t += 65536) kz[t] = z4;
  }
}

// -------------------------------------------------------------- phase 1 -----
// 256 wgs x 512 thr, 1024 rows/wg in 16 tiles of 64 rows.
// Per tile: stage x->LDS(bf16, swizzled), fused k/v GEMMs (W frags streamed
// from L2), elu+1 on k, transpose k,v into LDS (kT, vT reuses x buffer),
// kv += kT x vT into 128 AGPRs/wave. End: ksum atomics + kv partial writeout.
__global__ __launch_bounds__(512, 2) void phase1_kernel(
    const float* __restrict__ x, const u16* __restrict__ WkF,
    const u16* __restrict__ WvF, float* __restrict__ kvp, float* __restrict__ ksum,
    int P) {
  __shared__ __align__(16) u16 xv_l[16384];  // x (swizzled) then vT
  __shared__ __align__(16) u16 kT_l[16384];  // kT
  const int tid = threadIdx.x;
  const int lane = tid & 63;
  const int w = tid >> 6;    // wave 0..7
  const int m = lane & 15;   // MFMA m/n index
  const int q = lane >> 4;   // quad 0..3
  const int wg = blockIdx.x;

  const f32x4 fz = {0.f, 0.f, 0.f, 0.f};
  f32x4 kvacc[16][2];
#pragma unroll
  for (int tr = 0; tr < 16; ++tr) {
    kvacc[tr][0] = fz;
    kvacc[tr][1] = fz;
  }
  float ksl0 = 0.f, ksl1 = 0.f;

  for (int it = 0; it < 16; ++it) {
    const int row0 = wg * 1024 + it * 64;
    __syncthreads();  // protect xv_l/kT_l vs previous iteration's kv reads
    {  // stage x tile [64][256] -> bf16, d-block-major with r-XOR swizzle
      const int r = tid >> 3, a = tid & 7;
      const float4* xp = (const float4*)(x + (size_t)(row0 + r) * 256 + a * 32);
#pragma unroll
      for (int i = 0; i < 8; ++i) {
        float4 f = xp[i];
        int db = 4 * a + (i >> 1);
        int pos = db * 512 + ((r ^ (db & 7)) << 3) + 4 * (i & 1);
        uint2 v;
        v.x = bf16pk(f.x, f.y);
        v.y = bf16pk(f.z, f.w);
        *(uint2*)&xv_l[pos] = v;
      }
    }
    __syncthreads();
    f32x4 kacc[4][2], vacc[4][2];
#pragma unroll
    for (int rt = 0; rt < 4; ++rt) {
      kacc[rt][0] = fz; kacc[rt][1] = fz;
      vacc[rt][0] = fz; vacc[rt][1] = fz;
    }
#pragma unroll
    for (int ks = 0; ks < 8; ++ks) {
      const int fb = ((w * 8 + ks) * 2) * 512 + lane * 8;
      short8 wk0 = *(const short8*)(WkF + fb);
      short8 wk1 = *(const short8*)(WkF + fb + 512);
      short8 wv0 = *(const short8*)(WvF + fb);
      short8 wv1 = *(const short8*)(WvF + fb + 512);
      const int db = 4 * ks + q;
      const int sw = db & 7;
#pragma unroll
      for (int rt = 0; rt < 4; ++rt) {
        int r = 16 * rt + m;
        short8 af = *(const short8*)&xv_l[db * 512 + ((r ^ sw) << 3)];
        kacc[rt][0] = MFMA16(af, wk0, kacc[rt][0]);
        kacc[rt][1] = MFMA16(af, wk1, kacc[rt][1]);
        vacc[rt][0] = MFMA16(af, wv0, vacc[rt][0]);
        vacc[rt][1] = MFMA16(af, wv1, vacc[rt][1]);
      }
    }
    __syncthreads();  // all x reads done; xv_l reusable as vT
    // elu+1 on k, accumulate ksum, write kT and vT (C/D rows are contiguous
    // groups of 4 -> one b64 per (rt,ct)): element (col,row r) at
    // (r>>3)*2048 + col*8 + (r&7)
#pragma unroll
    for (int rt = 0; rt < 4; ++rt) {
#pragma unroll
      for (int ct = 0; ct < 2; ++ct) {
        f32x4 kk = kacc[rt][ct];
        float e0 = kk[0] > 0.f ? kk[0] + 1.f : __expf(kk[0]);
        float e1 = kk[1] > 0.f ? kk[1] + 1.f : __expf(kk[1]);
        float e2 = kk[2] > 0.f ? kk[2] + 1.f : __expf(kk[2]);
        float e3 = kk[3] > 0.f ? kk[3] + 1.f : __expf(kk[3]);
        if (ct == 0) ksl0 += (e0 + e1) + (e2 + e3);
        else         ksl1 += (e0 + e1) + (e2 + e3);
        int col = 32 * w + 16 * ct + m;
        int pos = (2 * rt + (q >> 1)) * 2048 + col * 8 + 4 * (q & 1);
        uint2 kp;
        kp.x = bf16pk(e0, e1);
        kp.y = bf16pk(e2, e3);
        *(uint2*)&kT_l[pos] = kp;
        f32x4 vv = vacc[rt][ct];
        uint2 vp;
        vp.x = bf16pk(vv[0], vv[1]);
        vp.y = bf16pk(vv[2], vv[3]);
        *(uint2*)&xv_l[pos] = vp;
      }
    }
    __syncthreads();
    // kv accumulation: wave w owns kv[:, 32w..32w+32)
#pragma unroll
    for (int kc = 0; kc < 2; ++kc) {
      const int rbb = (4 * kc + q) * 2048;
      short8 bf0 = *(const short8*)&xv_l[rbb + (32 * w + m) * 8];
      short8 bf1 = *(const short8*)&xv_l[rbb + (32 * w + 16 + m) * 8];
#pragma unroll
      for (int tr = 0; tr < 16; ++tr) {
        short8 af = *(const short8*)&kT_l[rbb + (16 * tr + m) * 8];
        kvacc[tr][0] = MFMA16(af, bf0, kvacc[tr][0]);
        kvacc[tr][1] = MFMA16(af, bf1, kvacc[tr][1]);
      }
    }
  }
  // ksum: reduce over quads (rows live in regs across q), one atomic per col
  float s0 = ksl0, s1 = ksl1;
  s0 += __shfl_xor(s0, 16); s0 += __shfl_xor(s0, 32);
  s1 += __shfl_xor(s1, 16); s1 += __shfl_xor(s1, 32);
  if (q == 0) {
    atomicAdd(&ksum[32 * w + m], s0);
    atomicAdd(&ksum[32 * w + 16 + m], s1);
  }
  // kv partial writeout
  float* dst = kvp + (size_t)((P == 256) ? wg : (wg & (P - 1))) * 65536;
  if (P == 256) {
#pragma unroll
    for (int tr = 0; tr < 16; ++tr)
#pragma unroll
      for (int ct = 0; ct < 2; ++ct)
#pragma unroll
        for (int e = 0; e < 4; ++e) {
          int i = 16 * tr + 4 * q + e;
          int j = 32 * w + 16 * ct + m;
          dst[i * 256 + j] = kvacc[tr][ct][e];
        }
  } else {
#pragma unroll
    for (int tr = 0; tr < 16; ++tr)
#pragma unroll
      for (int ct = 0; ct < 2; ++ct)
#pragma unroll
        for (int e = 0; e < 4; ++e) {
          int i = 16 * tr + 4 * q + e;
          int j = 32 * w + 16 * ct + m;
          atomicAdd(&dst[i * 256 + j], kvacc[tr][ct][e]);
        }
  }
}

// ---------------------------------------------------------------- mid -------
__global__ void mid1_kernel(const float* __restrict__ kvp, float* __restrict__ kv_red,
                            int P) {
  int id = blockIdx.x * 512 + threadIdx.x;  // 65536 threads, one element each
  float s = 0.f;
  for (int p = 0; p < P; ++p) s += kvp[(size_t)p * 65536 + id];
  kv_red[id] = s;
}

// M[i][j] = sum_c kv[i][c] * Wo[j][c]; store as pre-swizzled bf16 B-fragment
__global__ void mid2_kernel(const float* __restrict__ kv_red,
                            const float* __restrict__ Wo, u16* __restrict__ MF) {
  __shared__ float kr[256];
  const int i = blockIdx.x;    // k-dim (q channel)
  const int j = threadIdx.x;   // out channel
  kr[j] = kv_red[i * 256 + j];
  __syncthreads();
  float acc = 0.f;
  const float* wo = Wo + (size_t)j * 256;
#pragma unroll 8
  for (int c = 0; c < 256; ++c) acc += kr[c] * wo[c];
  MF[(((j >> 5) * 8 + (i >> 5)) * 2 + ((j >> 4) & 1)) * 512 + ((i >> 3) & 3) * 128 +
     (j & 15) * 8 + (i & 7)] = (u16)bf16_1(acc);
}

// -------------------------------------------------------------- phase 2 -----
// q = elu(xWq^T)+1; s = q@ksum (fp32, shuffle+LDS-atomic); out = (q@M)*z + bo
__global__ __launch_bounds__(512, 2) void phase2_kernel(
    const float* __restrict__ x, const u16* __restrict__ WqF,
    const u16* __restrict__ MF, const float* __restrict__ ksum,
    const float* __restrict__ bo, float* __restrict__ out) {
  __shared__ __align__(16) u16 xq_l[16384];  // x then q (same swizzle)
  __shared__ float s_l[64];
  const int tid = threadIdx.x;
  const int lane = tid & 63;
  const int w = tid >> 6;
  const int m = lane & 15;
  const int q = lane >> 4;
  const int wg = blockIdx.x;
  const f32x4 fz = {0.f, 0.f, 0.f, 0.f};

  short8 mf[8][2];  // persistent M fragments (64 VGPRs)
#pragma unroll
  for (int ks = 0; ks < 8; ++ks) {
    mf[ks][0] = *(const short8*)(MF + ((w * 8 + ks) * 2) * 512 + lane * 8);
    mf[ks][1] = *(const short8*)(MF + ((w * 8 + ks) * 2 + 1) * 512 + lane * 8);
  }
  const float ks0 = ksum[32 * w + m];
  const float ks1 = ksum[32 * w + 16 + m];
  const float b0 = bo[32 * w + m];
  const float b1 = bo[32 * w + 16 + m];

  for (int it = 0; it < 16; ++it) {
    const int row0 = wg * 1024 + it * 64;
    __syncthreads();
    {
      const int r = tid >> 3, a = tid & 7;
      const float4* xp = (const float4*)(x + (size_t)(row0 + r) * 256 + a * 32);
#pragma unroll
      for (int i = 0; i < 8; ++i) {
        float4 f = xp[i];
        int db = 4 * a + (i >> 1);
        int pos = db * 512 + ((r ^ (db & 7)) << 3) + 4 * (i & 1);
        uint2 v;
        v.x = bf16pk(f.x, f.y);
        v.y = bf16pk(f.z, f.w);
        *(uint2*)&xq_l[pos] = v;
      }
      if (tid < 64) s_l[tid] = 0.f;
    }
    __syncthreads();
    f32x4 qacc[4][2];
#pragma unroll
    for (int rt = 0; rt < 4; ++rt) { qacc[rt][0] = fz; qacc[rt][1] = fz; }
#pragma unroll
    for (int ks = 0; ks < 8; ++ks) {
      const int fb = ((w * 8 + ks) * 2) * 512 + lane * 8;
      short8 wq0 = *(const short8*)(WqF + fb);
      short8 wq1 = *(const short8*)(WqF + fb + 512);
      const int db = 4 * ks + q;
      const int sw = db & 7;
#pragma unroll
      for (int rt = 0; rt < 4; ++rt) {
        int r = 16 * rt + m;
        short8 af = *(const short8*)&xq_l[db * 512 + ((r ^ sw) << 3)];
        qacc[rt][0] = MFMA16(af, wq0, qacc[rt][0]);
        qacc[rt][1] = MFMA16(af, wq1, qacc[rt][1]);
      }
    }
    // elu+1 and s partials (fp32, pre-quantization)
#pragma unroll
    for (int rt = 0; rt < 4; ++rt) {
#pragma unroll
      for (int ct = 0; ct < 2; ++ct) {
        f32x4 a = qacc[rt][ct];
        a[0] = a[0] > 0.f ? a[0] + 1.f : __expf(a[0]);
        a[1] = a[1] > 0.f ? a[1] + 1.f : __expf(a[1]);
        a[2] = a[2] > 0.f ? a[2] + 1.f : __expf(a[2]);
        a[3] = a[3] > 0.f ? a[3] + 1.f : __expf(a[3]);
        qacc[rt][ct] = a;
      }
#pragma unroll
      for (int e = 0; e < 4; ++e) {
        float val = qacc[rt][0][e] * ks0 + qacc[rt][1][e] * ks1;
        val += __shfl_xor(val, 1);
        val += __shfl_xor(val, 2);
        val += __shfl_xor(val, 4);
        val += __shfl_xor(val, 8);
        if (m == 0) atomicAdd(&s_l[16 * rt + 4 * q + e], val);
      }
    }
    __syncthreads();  // x reads + s atomics done; reuse xq_l for q
#pragma unroll
    for (int rt = 0; rt < 4; ++rt)
#pragma unroll
      for (int ct = 0; ct < 2; ++ct) {
        int c = 32 * w + 16 * ct + m;
        int db = c >> 3;
        int sw = db & 7;
        int cw = c & 7;
#pragma unroll
        for (int e = 0; e < 4; ++e) {
          int r = 16 * rt + 4 * q + e;
          xq_l[db * 512 + ((r ^ sw) << 3) + cw] = (u16)bf16_1(qacc[rt][ct][e]);
        }
      }
    __syncthreads();
    f32x4 tacc[4][2];
#pragma unroll
    for (int rt = 0; rt < 4; ++rt) { tacc[rt][0] = fz; tacc[rt][1] = fz; }
#pragma unroll
    for (int ks = 0; ks < 8; ++ks) {
      const int db = 4 * ks + q;
      const int sw = db & 7;
#pragma unroll
      for (int rt = 0; rt < 4; ++rt) {
        int r = 16 * rt + m;
        short8 af = *(const short8*)&xq_l[db * 512 + ((r ^ sw) << 3)];
        tacc[rt][0] = MFMA16(af, mf[ks][0], tacc[rt][0]);
        tacc[rt][1] = MFMA16(af, mf[ks][1], tacc[rt][1]);
      }
    }
#pragma unroll
    for (int rt = 0; rt < 4; ++rt)
#pragma unroll
      for (int e = 0; e < 4; ++e) {
        int r = 16 * rt + 4 * q + e;
        float z = __builtin_amdgcn_rcpf(fmaxf(s_l[r], 1e-6f));
        float* op = out + (size_t)(row0 + r) * 256 + 32 * w;
        op[m] = tacc[rt][0][e] * z + b0;
        op[16 + m] = tacc[rt][1][e] * z + b1;
      }
  }
}

// ---------------------------------------------------------------- host ------
extern "C" void kernel_launch(void* const* d_in, const int* in_sizes, int n_in,
                              void* d_out, int out_size, void* d_ws, size_t ws_size,
                              hipStream_t stream) {
  const float* x = (const float*)d_in[0];
  const float* Wq = (const float*)d_in[1];
  const float* Wk = (const float*)d_in[2];
  const float* Wv = (const float*)d_in[3];
  const float* Wo = (const float*)d_in[4];
  const float* bo = (const float*)d_in[5];
  float* out = (float*)d_out;

  // ws layout: kvp[P*65536 f] | ksum[256 f] | kv_red[65536 f] | MF,WqF,WkF,WvF (u16)
  const size_t fixedB = 1024 + 262144 + 4 * 131072;
  int P = 256;
  while (P > 1 && (size_t)P * 262144 + fixedB > ws_size) P >>= 1;

  char* base = (char*)d_ws;
  float* kvp = (float*)base;
  float* ksum = (float*)(base + (size_t)P * 262144);
  float* kvred = ksum + 256;
  u16* MF = (u16*)(kvred + 65536);
  u16* WqF = MF + 65536;
  u16* WkF = WqF + 65536;
  u16* WvF = WkF + 65536;

  prep_kernel<<<256, 256, 0, stream>>>(Wq, Wk, Wv, WqF, WkF, WvF, kvp, ksum, P);
  phase1_kernel<<<256, 512, 0, stream>>>(x, WkF, WvF, kvp, ksum, P);
  mid1_kernel<<<128, 512, 0, stream>>>(kvp, kvred, P);
  mid2_kernel<<<256, 256, 0, stream>>>(kvred, Wo, MF);
  phase2_kernel<<<256, 512, 0, stream>>>(x, WqF, MF, ksum, bo, out);
}